// Round 9
// baseline (576.531 us; speedup 1.0000x reference)
//
#include <hip/hip_runtime.h>
#include <stdint.h>

typedef unsigned int uint32;
typedef unsigned long long u64;

#define BATCH 8
#define LDIM 4096
#define CDIM 128

typedef __attribute__((ext_vector_type(4))) int i32x4;
typedef __attribute__((ext_vector_type(16))) int i32x16;

// ---- workspace layout (bytes) ----
#define DIG1_OFF    0ull          /* i8 digits f1, frag-order: 16 MB */
#define DIG2_OFF    16777216ull   /* i8 digits f2 */
#define ROWPART_OFF 33554432ull   /* float2 [8][4096][32] = 8 MB */
#define COLPART_OFF 41943040ull   /* float2 [8][4096][32] = 8 MB */
#define LSER_OFF    50331648ull   /* double [8][4096] */
#define LSEC_OFF    50593792ull
#define RPACK_OFF   50855936ull   /* u64 [8][4096] */
#define CPACK_OFF   51118080ull
#define WS_NEEDED   51380224ull

// lam2 = log2(e) * 10 * (t01*2^-15 + t23*2^-29)  (log2-domain logits)
#define C1L (3.0517578125e-04 * 1.4426950408889634)
#define C2L (1.862645149230957e-08 * 1.4426950408889634)
#define LOG2_02 (-2.3219280948873623)   /* log2(0.2) */

#define CROW(r, kgv) (((r)&3) + 8*((r)>>2) + 4*(kgv))

__device__ __forceinline__ uint32 fkey(float f) {
    uint32 u = __float_as_uint(f);
    return (u & 0x80000000u) ? ~u : (u | 0x80000000u);
}
__device__ __forceinline__ float keyf(uint32 k) {
    uint32 u = (k & 0x80000000u) ? (k ^ 0x80000000u) : ~k;
    return __uint_as_float(u);
}
__device__ __forceinline__ i32x16 mfma_i8(i32x4 a, i32x4 b, i32x16 c) {
    return __builtin_amdgcn_mfma_i32_32x32x32_i8(a, b, c, 0, 0, 0);
}
__device__ __forceinline__ u64 umax64(u64 a, u64 b) { return a > b ? a : b; }

__global__ void fill_sentinel(float* out, int nelem) {
    int i = blockIdx.x * 256 + threadIdx.x;
    if (i < nelem) out[i] = 12345.0f;
}

__global__ void init_packs(u64* __restrict__ rowpack, u64* __restrict__ colpack) {
    int idx = blockIdx.x * 256 + threadIdx.x;
    if (idx < BATCH * LDIM) { rowpack[idx] = 0ull; colpack[idx] = 0ull; }
}

// Quantize fp32 -> 4 exact base-128 signed digits of round(x*2^25).
__global__ __launch_bounds__(256) void quant_kernel(const float* __restrict__ f1,
                                                    const float* __restrict__ f2,
                                                    char* __restrict__ dig)
{
    int tid = blockIdx.x * 256 + threadIdx.x;
    int l31 = tid & 31;
    int kg  = (tid >> 5) & 1;
    int kc  = (tid >> 6) & 3;
    int rb  = (tid >> 8) & 1;
    int blk = (tid >> 9) & 63;
    int n   = (tid >> 15) & 7;
    int inp = tid >> 18;
    int row = blk * 64 + rb * 32 + l31;

    const float* src = (inp ? f2 : f1) + ((size_t)(n * LDIM + row)) * CDIM + kc * 32 + kg * 16;
    char* dstc = dig + (inp ? DIG2_OFF : DIG1_OFF)
               + (((size_t)n * 64 + blk) * 4 + kc) * 8192;
    int gpos = rb * 64 + kg * 32 + l31;

    float4 v0 = ((const float4*)src)[0];
    float4 v1 = ((const float4*)src)[1];
    float4 v2 = ((const float4*)src)[2];
    float4 v3 = ((const float4*)src)[3];
    float xs[16] = {v0.x,v0.y,v0.z,v0.w, v1.x,v1.y,v1.z,v1.w,
                    v2.x,v2.y,v2.z,v2.w, v3.x,v3.y,v3.z,v3.w};
    uint32 wds[4][4] = {{0,0,0,0},{0,0,0,0},{0,0,0,0},{0,0,0,0}};
#pragma unroll
    for (int e = 0; e < 16; e++) {
        int q = __float2int_rn(xs[e] * 33554432.0f);
        int d0 = (q + (1 << 20)) >> 21; q -= d0 << 21;
        int d1 = (q + (1 << 13)) >> 14; q -= d1 << 14;
        int d2 = (q + (1 << 6)) >> 7;   q -= d2 << 7;
        int sh = (e & 3) * 8;
        wds[0][e >> 2] |= (uint32)(d0 & 255) << sh;
        wds[1][e >> 2] |= (uint32)(d1 & 255) << sh;
        wds[2][e >> 2] |= (uint32)(d2 & 255) << sh;
        wds[3][e >> 2] |= (uint32)(q  & 255) << sh;
    }
#pragma unroll
    for (int p = 0; p < 4; p++) {
        *(int4*)(dstc + (size_t)(p * 128 + gpos) * 16) =
            make_int4(wds[p][0], wds[p][1], wds[p][2], wds[p][3]);
    }
}

// 8 waves = (wr in {0,1}) x (wc in {0..3}); each wave owns 64x32 output with
// all 4 digit banks. K-loop is REGISTER-DIRECT: fragments loaded straight
// from global (L1/L2-resident digits) with software-pipelined ping-pong;
// no LDS, no barriers in the loop. LDS only for epilogue.
template <int PASS>
__global__ __launch_bounds__(512, 2) void gemm_kernel(
    const char* __restrict__ dig,
    float2* __restrict__ rowpart, float2* __restrict__ colpart,
    const double* __restrict__ lse_row, const double* __restrict__ lse_col,
    u64* __restrict__ rowpack, u64* __restrict__ colpack)
{
    __shared__ __align__(16) char smp[(PASS == 1) ? 74752 : 3072];
    // PASS1: trf f32[128][129] @0 (66048B), rstat f2[4][128] @66560,
    //        cpart f2[4][128] @70656
    // PASS2: lserd @0 (1024), lsecd @1024, lserf @2048, lsecf @2560

    int wg = blockIdx.x;
    int swz = (wg & 7) * 1024 + (wg >> 3);    // one batch per XCD
    int n  = swz >> 10;
    int tM = (swz >> 5) & 31;
    int tN = swz & 31;

    const int t = threadIdx.x;
    const int lane = t & 63, w = t >> 6;
    const int wr = w >> 2, wc = w & 3;
    const int l31 = lane & 31, kg = lane >> 5;

    double* lserd = (double*)(smp);
    double* lsecd = (double*)(smp + 1024);
    float*  lserf = (float*)(smp + 2048);
    float*  lsecf = (float*)(smp + 2560);
    if (PASS == 2) {
        if (t < 128) {
            double d = lse_row[(size_t)n * LDIM + tM * 128 + t];
            lserd[t] = d; lserf[t] = (float)d;
        } else if (t < 256) {
            int c = t - 128;
            double d = lse_col[(size_t)n * LDIM + tN * 128 + c];
            lsecd[c] = d; lsecf[c] = (float)d;
        }
    }

    // per-wave global fragment bases (kc advances by 8192)
    const char* gA = dig + DIG1_OFF
                   + (((size_t)n * 64 + tM * 2 + wr) * 4) * 8192
                   + wr * 0 + lane * 16;
    const char* gB = dig + DIG2_OFF
                   + (((size_t)n * 64 + tN * 2 + (wc >> 1)) * 4) * 8192
                   + (wc & 1) * 1024 + lane * 16;

    const i32x16 zero16 = {0,0,0,0,0,0,0,0,0,0,0,0,0,0,0,0};
    i32x16 acc[2][4];
#pragma unroll
    for (int sm = 0; sm < 2; sm++)
#pragma unroll
        for (int k = 0; k < 4; k++) acc[sm][k] = zero16;

    i32x4 aF[2][2][4], bF[2][4];    // [buf][sm][p] / [buf][p]; static under unroll
#pragma unroll
    for (int p = 0; p < 4; p++)
        bF[0][p] = *(const i32x4*)(gB + p * 2048);
#pragma unroll
    for (int sm = 0; sm < 2; sm++)
#pragma unroll
        for (int p = 0; p < 4; p++)
            aF[0][sm][p] = *(const i32x4*)(gA + p * 2048 + sm * 1024);

#pragma unroll
    for (int kc = 0; kc < 4; kc++) {
        const int cur = kc & 1, nxt = cur ^ 1;
        if (kc < 3) {
            const char* gAn = gA + (size_t)(kc + 1) * 8192;
            const char* gBn = gB + (size_t)(kc + 1) * 8192;
#pragma unroll
            for (int p = 0; p < 4; p++)
                bF[nxt][p] = *(const i32x4*)(gBn + p * 2048);
#pragma unroll
            for (int sm = 0; sm < 2; sm++)
#pragma unroll
                for (int p = 0; p < 4; p++)
                    aF[nxt][sm][p] = *(const i32x4*)(gAn + p * 2048 + sm * 1024);
        }
        __builtin_amdgcn_s_setprio(1);
#pragma unroll
        for (int sm = 0; sm < 2; sm++) {
            acc[sm][0] = mfma_i8(aF[cur][sm][0], bF[cur][0], acc[sm][0]);   // T0
            acc[sm][1] = mfma_i8(aF[cur][sm][0], bF[cur][1], acc[sm][1]);   // T1
            acc[sm][1] = mfma_i8(aF[cur][sm][1], bF[cur][0], acc[sm][1]);
            acc[sm][2] = mfma_i8(aF[cur][sm][0], bF[cur][2], acc[sm][2]);   // T2
            acc[sm][2] = mfma_i8(aF[cur][sm][1], bF[cur][1], acc[sm][2]);
            acc[sm][2] = mfma_i8(aF[cur][sm][2], bF[cur][0], acc[sm][2]);
            acc[sm][3] = mfma_i8(aF[cur][sm][0], bF[cur][3], acc[sm][3]);   // T3
            acc[sm][3] = mfma_i8(aF[cur][sm][1], bF[cur][2], acc[sm][3]);
            acc[sm][3] = mfma_i8(aF[cur][sm][2], bF[cur][1], acc[sm][3]);
            acc[sm][3] = mfma_i8(aF[cur][sm][3], bF[cur][0], acc[sm][3]);
        }
        __builtin_amdgcn_s_setprio(0);
    }

    const int col = wc * 32 + l31;

    if (PASS == 1) {
        float* trf = (float*)smp;                       // [128][129]
        float2* rstat = (float2*)(smp + 66560);         // [4][128]
        float2* cpart = (float2*)(smp + 70656);         // [4][128]

        const float c1f = (float)C1L, c2f = (float)C2L;
        float lamf[2][16];
#pragma unroll
        for (int sm = 0; sm < 2; sm++)
#pragma unroll
            for (int r = 0; r < 16; r++) {
                int t01 = acc[sm][0][r] * 128 + acc[sm][1][r];
                int t23 = acc[sm][2][r] * 128 + acc[sm][3][r];
                float lf = fmaf((float)t23, c2f, (float)t01 * c1f);
                lamf[sm][r] = lf;
                int row = wr * 64 + sm * 32 + CROW(r, kg);
                trf[row * 129 + col] = lf;
            }
        float cm = lamf[0][0];
#pragma unroll
        for (int sm = 0; sm < 2; sm++)
#pragma unroll
            for (int r = 0; r < 16; r++) cm = fmaxf(cm, lamf[sm][r]);
        float cs = 0.f;
#pragma unroll
        for (int sm = 0; sm < 2; sm++)
#pragma unroll
            for (int r = 0; r < 16; r++) cs += exp2f(lamf[sm][r] - cm);
        cpart[(wr * 2 + kg) * 128 + col] = make_float2(cm, cs);
        __syncthreads();

        {   // row stats: thread -> (row = t&127, seg = t>>7), 32 cols each
            int row = t & 127, seg = t >> 7;
            const float* rp = trf + row * 129 + seg * 32;
            float v[32];
#pragma unroll
            for (int j = 0; j < 32; j++) v[j] = rp[j];
            float rm = v[0];
#pragma unroll
            for (int j = 1; j < 32; j++) rm = fmaxf(rm, v[j]);
            float rs = 0.f;
#pragma unroll
            for (int j = 0; j < 32; j++) rs += exp2f(v[j] - rm);
            rstat[seg * 128 + row] = make_float2(rm, rs);
        }
        __syncthreads();
        if (t < 128) {
            float2 a = rstat[t], b = rstat[128 + t], c = rstat[256 + t], d = rstat[384 + t];
            float M = fmaxf(fmaxf(a.x, b.x), fmaxf(c.x, d.x));
            float S = a.y * exp2f(a.x - M) + b.y * exp2f(b.x - M)
                    + c.y * exp2f(c.x - M) + d.y * exp2f(d.x - M);
            rowpart[((size_t)n * LDIM + tM * 128 + t) * 32 + tN] = make_float2(M, S);
        } else if (t < 256) {
            int c0 = t - 128;
            float2 a = cpart[c0], b = cpart[128 + c0], c = cpart[256 + c0], d = cpart[384 + c0];
            float M = fmaxf(fmaxf(a.x, b.x), fmaxf(c.x, d.x));
            float S = a.y * exp2f(a.x - M) + b.y * exp2f(b.x - M)
                    + c.y * exp2f(c.x - M) + d.y * exp2f(d.x - M);
            colpart[((size_t)n * LDIM + tN * 128 + c0) * 32 + tM] = make_float2(M, S);
        }
    } else {
        // PASS 2: in-register t01 filter (margin 17 conservative), exact keys
        // for rare candidates, direct global atomicMax.
        __syncthreads();   // lse tables visible
        const float two_c1f = (float)(2.0 * C1L);
        const float scol = lsecf[col] + (float)LOG2_02 - 17.0f;
        const double lcd = lsecd[col];
#pragma unroll
        for (int sm = 0; sm < 2; sm++)
#pragma unroll
            for (int r = 0; r < 16; r++) {
                int row = wr * 64 + sm * 32 + CROW(r, kg);
                int t01 = acc[sm][0][r] * 128 + acc[sm][1][r];
                float lv = (float)t01 * two_c1f;
                if (lv > lserf[row] + scol) {
                    int t23 = acc[sm][2][r] * 128 + acc[sm][3][r];
                    double l2 = (double)t01 * C1L + (double)t23 * C2L;
                    float gf = (float)(2.0 * l2 - lserd[row] - lcd);
                    u64 key = ((u64)fkey(gf)) << 32;
                    atomicMax(&rowpack[(size_t)n * LDIM + tM * 128 + row],
                              key | (uint32)(~(uint32)(tN * 128 + col)));
                    atomicMax(&colpack[(size_t)n * LDIM + tN * 128 + col],
                              key | (uint32)(~(uint32)(tM * 128 + row)));
                }
            }
    }
}

__global__ __launch_bounds__(256) void merge_kernel(
    const float2* __restrict__ rowpart, const float2* __restrict__ colpart,
    double* __restrict__ lse_row, double* __restrict__ lse_col)
{
    int idx = blockIdx.x * 256 + threadIdx.x;
    const float2* src = (idx < BATCH * LDIM) ? rowpart : colpart;
    double* dst = (idx < BATCH * LDIM) ? lse_row : lse_col;
    int i = idx & (BATCH * LDIM - 1);
    double M = -1e300;
#pragma unroll
    for (int j = 0; j < 32; j++) M = fmax(M, (double)src[(size_t)i * 32 + j].x);
    double S = 0.0;
#pragma unroll
    for (int j = 0; j < 32; j++) {
        float2 ms = src[(size_t)i * 32 + j];
        S += (double)ms.y * exp2((double)ms.x - M);
    }
    dst[i] = M + log2(S);
}

__global__ __launch_bounds__(256) void out_kernel(
    const float* __restrict__ f1, const float* __restrict__ f2,
    const u64* __restrict__ rowpack, const u64* __restrict__ colpack,
    float* __restrict__ out)
{
    int n = blockIdx.y;
    int l0 = blockIdx.x * 64;
    int t = threadIdx.x;
    __shared__ int s_sh[64];
    __shared__ int m_sh[64];
    __shared__ float tile[64][129];
    if (t < 64) {
        u64 rp = rowpack[(size_t)n * LDIM + l0 + t];
        uint32 skey = (uint32)(rp >> 32);
        uint32 s = (~(uint32)rp) & 4095u;
        u64 cp = colpack[(size_t)n * LDIM + s];
        double g2 = (double)keyf(skey);
        int match = (((uint32)(cp >> 32)) == skey) && (g2 > LOG2_02);
        s_sh[t] = (int)s;
        m_sh[t] = match;
    }
    __syncthreads();
#pragma unroll
    for (int i = 0; i < 32; i++) {
        int idx = i * 256 + t;
        int lloc = idx >> 7, ch = idx & 127;
        float v = f1[((size_t)n * LDIM + l0 + lloc) * CDIM + ch];
        if (m_sh[lloc]) v -= f2[((size_t)n * LDIM + s_sh[lloc]) * CDIM + ch];
        tile[lloc][ch] = v;
    }
    __syncthreads();
#pragma unroll
    for (int i = 0; i < 32; i++) {
        int ch = i * 4 + (t >> 6), lw = t & 63;
        out[((size_t)n * CDIM + ch) * LDIM + l0 + lw] = tile[lw][ch];
    }
}

extern "C" void kernel_launch(void* const* d_in, const int* in_sizes, int n_in,
                              void* d_out, int out_size, void* d_ws, size_t ws_size,
                              hipStream_t stream)
{
    const float* f1 = (const float*)d_in[0];
    const float* f2 = (const float*)d_in[1];
    float* out = (float*)d_out;
    char* ws = (char*)d_ws;
    char* dig = ws;

    if (ws_size < WS_NEEDED) {
        fill_sentinel<<<(out_size + 255) / 256, 256, 0, stream>>>(out, out_size);
        return;
    }

    float2* rowpart = (float2*)(ws + ROWPART_OFF);
    float2* colpart = (float2*)(ws + COLPART_OFF);
    double* lse_row = (double*)(ws + LSER_OFF);
    double* lse_col = (double*)(ws + LSEC_OFF);
    u64* rowpack = (u64*)(ws + RPACK_OFF);
    u64* colpack = (u64*)(ws + CPACK_OFF);

    quant_kernel<<<dim3(2048), dim3(256), 0, stream>>>(f1, f2, dig);
    init_packs<<<dim3(128), dim3(256), 0, stream>>>(rowpack, colpack);
    gemm_kernel<1><<<dim3(8192), dim3(512), 0, stream>>>(
        dig, rowpart, colpart, lse_row, lse_col, rowpack, colpack);
    merge_kernel<<<dim3(256), dim3(256), 0, stream>>>(rowpart, colpart, lse_row, lse_col);
    gemm_kernel<2><<<dim3(8192), dim3(512), 0, stream>>>(
        dig, rowpart, colpart, lse_row, lse_col, rowpack, colpack);
    out_kernel<<<dim3(LDIM / 64, BATCH), dim3(256), 0, stream>>>(
        f1, f2, rowpack, colpack, out);
}

// Round 10
// 447.154 us; speedup vs baseline: 1.2893x; 1.2893x over previous
//
#include <hip/hip_runtime.h>
#include <stdint.h>

typedef unsigned int uint32;
typedef unsigned long long u64;

#define BATCH 8
#define LDIM 4096
#define CDIM 128

typedef __attribute__((ext_vector_type(4))) int i32x4;
typedef __attribute__((ext_vector_type(16))) int i32x16;

// ---- workspace layout (bytes) ----
#define DIG1_OFF  0ull           /* i8 digits f1, LDS-order: 16 MB */
#define DIG2_OFF  16777216ull    /* i8 digits f2 */
#define RPF_OFF   33554432ull    /* float [8][4096][32] partial row LSE, 4 MB */
#define CPF_OFF   37748736ull    /* float [8][4096][32] partial col LSE, 4 MB */
#define LSER_OFF  41943040ull    /* double [8][4096] */
#define LSEC_OFF  42205184ull
#define RPACK_OFF 42467328ull    /* u64 [8][4096] */
#define CPACK_OFF 42729472ull
#define CCNT_OFF  42991616ull    /* u32 counter (+pad) */
#define CIDX_OFF  42995712ull    /* u32 [CAND_CAP] */
#define CT_OFF    45755712ull    /* u64 [CAND_CAP] */
#define WS_NEEDED 51380224ull    /* layout ends 51,275,712 */

#define CAND_CAP 690000u
#define CMARGIN 2.40f

// lam2 = log2(e) * 10 * (t01*2^-15 + t23*2^-29)  (log2-domain logits)
#define C1L (3.0517578125e-04 * 1.4426950408889634)
#define C2L (1.862645149230957e-08 * 1.4426950408889634)
#define LOG2_02 (-2.3219280948873623)   /* log2(0.2) */

#define CROW(r, kgv) (((r)&3) + 8*((r)>>2) + 4*(kgv))

__device__ __forceinline__ uint32 fkey(float f) {
    uint32 u = __float_as_uint(f);
    return (u & 0x80000000u) ? ~u : (u | 0x80000000u);
}
__device__ __forceinline__ float keyf(uint32 k) {
    uint32 u = (k & 0x80000000u) ? (k ^ 0x80000000u) : ~k;
    return __uint_as_float(u);
}
__device__ __forceinline__ i32x16 mfma_i8(i32x4 a, i32x4 b, i32x16 c) {
    return __builtin_amdgcn_mfma_i32_32x32x32_i8(a, b, c, 0, 0, 0);
}
__device__ __forceinline__ void load_lds16(const char* g, char* l) {
    __builtin_amdgcn_global_load_lds((__attribute__((address_space(1))) void*)(g),
                                     (__attribute__((address_space(3))) void*)(l), 16, 0, 0);
}
__device__ __forceinline__ u64 umax64(u64 a, u64 b) { return a > b ? a : b; }

__global__ void fill_sentinel(float* out, int nelem) {
    int i = blockIdx.x * 256 + threadIdx.x;
    if (i < nelem) out[i] = 12345.0f;
}

__global__ void init_packs(u64* __restrict__ rowpack, u64* __restrict__ colpack,
                           uint32* __restrict__ ccount) {
    int idx = blockIdx.x * 256 + threadIdx.x;
    if (idx < BATCH * LDIM) { rowpack[idx] = 0ull; colpack[idx] = 0ull; }
    if (idx == 0) ccount[0] = 0u;
}

// Quantize fp32 -> 4 exact base-128 signed digits of round(x*2^25).
__global__ __launch_bounds__(256) void quant_kernel(const float* __restrict__ f1,
                                                    const float* __restrict__ f2,
                                                    char* __restrict__ dig)
{
    int tid = blockIdx.x * 256 + threadIdx.x;
    int l31 = tid & 31;
    int kg  = (tid >> 5) & 1;
    int kc  = (tid >> 6) & 3;
    int rb  = (tid >> 8) & 1;
    int blk = (tid >> 9) & 63;
    int n   = (tid >> 15) & 7;
    int inp = tid >> 18;
    int row = blk * 64 + rb * 32 + l31;

    const float* src = (inp ? f2 : f1) + ((size_t)(n * LDIM + row)) * CDIM + kc * 32 + kg * 16;
    char* dstc = dig + (inp ? DIG2_OFF : DIG1_OFF)
               + (((size_t)n * 64 + blk) * 4 + kc) * 8192;
    int gpos = rb * 64 + kg * 32 + l31;

    float4 v0 = ((const float4*)src)[0];
    float4 v1 = ((const float4*)src)[1];
    float4 v2 = ((const float4*)src)[2];
    float4 v3 = ((const float4*)src)[3];
    float xs[16] = {v0.x,v0.y,v0.z,v0.w, v1.x,v1.y,v1.z,v1.w,
                    v2.x,v2.y,v2.z,v2.w, v3.x,v3.y,v3.z,v3.w};
    uint32 wds[4][4] = {{0,0,0,0},{0,0,0,0},{0,0,0,0},{0,0,0,0}};
#pragma unroll
    for (int e = 0; e < 16; e++) {
        int q = __float2int_rn(xs[e] * 33554432.0f);
        int d0 = (q + (1 << 20)) >> 21; q -= d0 << 21;
        int d1 = (q + (1 << 13)) >> 14; q -= d1 << 14;
        int d2 = (q + (1 << 6)) >> 7;   q -= d2 << 7;
        int sh = (e & 3) * 8;
        wds[0][e >> 2] |= (uint32)(d0 & 255) << sh;
        wds[1][e >> 2] |= (uint32)(d1 & 255) << sh;
        wds[2][e >> 2] |= (uint32)(d2 & 255) << sh;
        wds[3][e >> 2] |= (uint32)(q  & 255) << sh;
    }
#pragma unroll
    for (int p = 0; p < 4; p++) {
        *(int4*)(dstc + (size_t)(p * 128 + gpos) * 16) =
            make_int4(wds[p][0], wds[p][1], wds[p][2], wds[p][3]);
    }
}

// FUSED single GEMM pass: exact i8-digit products -> fp32 stats partials
// (log2 LSE per tile) + candidate emission (elements within CMARGIN bits of
// BOTH tile row max and tile col max; superset of all m>0.2 elements).
__global__ __launch_bounds__(512, 2) void gemm_fused(
    const char* __restrict__ dig,
    float* __restrict__ rpf, float* __restrict__ cpf,
    uint32* __restrict__ ccount, uint32* __restrict__ cidx, u64* __restrict__ ct)
{
    __shared__ __align__(16) char smp[75776];
    // stage: 2 bufs x 32KB @0..65536
    // epilogue reuse: trf f32[128][129] @0 (66048), rstat f2[4][128] @66560,
    // cpart f2[4][128] @70656, rowMaxF[128] @74752, colMaxF[128] @75264
    __shared__ uint32 blkCount, blkBase;

    int wg = blockIdx.x;
    int swz = (wg & 7) * 1024 + (wg >> 3);    // one batch per XCD
    int n  = swz >> 10;
    int tM = (swz >> 5) & 31;
    int tN = swz & 31;

    const int t = threadIdx.x;
    const int lane = t & 63, w = t >> 6;
    const int wr = w >> 2, wc = w & 3;
    const int l31 = lane & 31, kg = lane >> 5;

    const i32x16 zero16 = {0,0,0,0,0,0,0,0,0,0,0,0,0,0,0,0};
    i32x16 acc[2][4];
#pragma unroll
    for (int sm = 0; sm < 2; sm++)
#pragma unroll
        for (int k = 0; k < 4; k++) acc[sm][k] = zero16;

    auto stage_step = [&](int kc, int buf) {
#pragma unroll
        for (int i = 0; i < 4; i++) {
            int blk = (i < 2) ? (tM * 2 + i) : (tN * 2 + (i - 2));
            const char* src = dig + ((i < 2) ? DIG1_OFF : DIG2_OFF)
                            + (((size_t)n * 64 + blk) * 4 + kc) * 8192 + t * 16;
            load_lds16(src, smp + buf * 32768 + i * 8192 + t * 16);
        }
    };

    stage_step(0, 0);
    for (int kc = 0; kc < 4; kc++) {
        int buf = kc & 1;
        __syncthreads();
        if (kc < 3) stage_step(kc + 1, buf ^ 1);
        const char* Ab = smp + buf * 32768 + wr * 8192;
        const char* Bb = smp + buf * 32768 + 16384 + (wc >> 1) * 8192 + (wc & 1) * 1024;
        i32x4 aF[2][4], bF[4];
#pragma unroll
        for (int p = 0; p < 4; p++)
            bF[p] = *(const i32x4*)(Bb + p * 2048 + lane * 16);
#pragma unroll
        for (int sm = 0; sm < 2; sm++)
#pragma unroll
            for (int p = 0; p < 4; p++)
                aF[sm][p] = *(const i32x4*)(Ab + p * 2048 + sm * 1024 + lane * 16);
#pragma unroll
        for (int sm = 0; sm < 2; sm++) {
            acc[sm][0] = mfma_i8(aF[sm][0], bF[0], acc[sm][0]);   // T0
            acc[sm][1] = mfma_i8(aF[sm][0], bF[1], acc[sm][1]);   // T1
            acc[sm][1] = mfma_i8(aF[sm][1], bF[0], acc[sm][1]);
            acc[sm][2] = mfma_i8(aF[sm][0], bF[2], acc[sm][2]);   // T2
            acc[sm][2] = mfma_i8(aF[sm][1], bF[1], acc[sm][2]);
            acc[sm][2] = mfma_i8(aF[sm][2], bF[0], acc[sm][2]);
            acc[sm][3] = mfma_i8(aF[sm][0], bF[3], acc[sm][3]);   // T3
            acc[sm][3] = mfma_i8(aF[sm][1], bF[2], acc[sm][3]);
            acc[sm][3] = mfma_i8(aF[sm][2], bF[1], acc[sm][3]);
            acc[sm][3] = mfma_i8(aF[sm][3], bF[0], acc[sm][3]);
        }
    }

    const int col = wc * 32 + l31;

    // exact integer pairs (kept live for emission) + fp32 logits for stats
    int t01v[2][16], t23v[2][16];
    float lamf[2][16];
    const float c1f = (float)C1L, c2f = (float)C2L;
#pragma unroll
    for (int sm = 0; sm < 2; sm++)
#pragma unroll
        for (int r = 0; r < 16; r++) {
            t01v[sm][r] = acc[sm][0][r] * 128 + acc[sm][1][r];
            t23v[sm][r] = acc[sm][2][r] * 128 + acc[sm][3][r];
            lamf[sm][r] = fmaf((float)t23v[sm][r], c2f, (float)t01v[sm][r] * c1f);
        }

    float* trf = (float*)smp;                       // [128][129]
    float2* rstat = (float2*)(smp + 66560);         // [4][128]
    float2* cpart = (float2*)(smp + 70656);         // [4][128]
    float* rowMaxF = (float*)(smp + 74752);         // [128]
    float* colMaxF = (float*)(smp + 75264);         // [128]

    __syncthreads();   // all frag reads done; stage region reusable
    if (t == 0) blkCount = 0u;

#pragma unroll
    for (int sm = 0; sm < 2; sm++)
#pragma unroll
        for (int r = 0; r < 16; r++) {
            int row = wr * 64 + sm * 32 + CROW(r, kg);
            trf[row * 129 + col] = lamf[sm][r];
        }
    {
        float cm = lamf[0][0];
#pragma unroll
        for (int sm = 0; sm < 2; sm++)
#pragma unroll
            for (int r = 0; r < 16; r++) cm = fmaxf(cm, lamf[sm][r]);
        float cs = 0.f;
#pragma unroll
        for (int sm = 0; sm < 2; sm++)
#pragma unroll
            for (int r = 0; r < 16; r++) cs += exp2f(lamf[sm][r] - cm);
        cpart[(wr * 2 + kg) * 128 + col] = make_float2(cm, cs);
    }
    __syncthreads();

    {   // row stats: thread -> (row = t&127, seg = t>>7), 32 cols each
        int row = t & 127, seg = t >> 7;
        const float* rp = trf + row * 129 + seg * 32;
        float v[32];
#pragma unroll
        for (int j = 0; j < 32; j++) v[j] = rp[j];
        float rm = v[0];
#pragma unroll
        for (int j = 1; j < 32; j++) rm = fmaxf(rm, v[j]);
        float rs = 0.f;
#pragma unroll
        for (int j = 0; j < 32; j++) rs += exp2f(v[j] - rm);
        rstat[seg * 128 + row] = make_float2(rm, rs);
    }
    __syncthreads();
    if (t < 128) {
        float2 a = rstat[t], b = rstat[128 + t], c = rstat[256 + t], d = rstat[384 + t];
        float M = fmaxf(fmaxf(a.x, b.x), fmaxf(c.x, d.x));
        float S = a.y * exp2f(a.x - M) + b.y * exp2f(b.x - M)
                + c.y * exp2f(c.x - M) + d.y * exp2f(d.x - M);
        rowMaxF[t] = M;
        rpf[((size_t)n * LDIM + tM * 128 + t) * 32 + tN] = M + log2f(S);
    } else if (t < 256) {
        int c0 = t - 128;
        float2 a = cpart[c0], b = cpart[128 + c0], c = cpart[256 + c0], d = cpart[384 + c0];
        float M = fmaxf(fmaxf(a.x, b.x), fmaxf(c.x, d.x));
        float S = a.y * exp2f(a.x - M) + b.y * exp2f(b.x - M)
                + c.y * exp2f(c.x - M) + d.y * exp2f(d.x - M);
        colMaxF[c0] = M;
        cpf[((size_t)n * LDIM + tN * 128 + c0) * 32 + tM] = M + log2f(S);
    }
    __syncthreads();   // maxima ready

    // ---- candidate scan: count, reserve, write ----
    const float cthr = colMaxF[col] - CMARGIN;
    uint32 myCnt = 0;
#pragma unroll
    for (int sm = 0; sm < 2; sm++)
#pragma unroll
        for (int r = 0; r < 16; r++) {
            int row = wr * 64 + sm * 32 + CROW(r, kg);
            if (lamf[sm][r] >= rowMaxF[row] - CMARGIN && lamf[sm][r] >= cthr) myCnt++;
        }
    uint32 myBase = 0;
    if (myCnt) myBase = atomicAdd(&blkCount, myCnt);
    __syncthreads();
    if (t == 0) blkBase = atomicAdd(ccount, blkCount);
    __syncthreads();
    if (myCnt) {
        uint32 p = blkBase + myBase;
        const uint32 colG = (uint32)(tN * 128 + col);
#pragma unroll
        for (int sm = 0; sm < 2; sm++)
#pragma unroll
            for (int r = 0; r < 16; r++) {
                int row = wr * 64 + sm * 32 + CROW(r, kg);
                if (lamf[sm][r] >= rowMaxF[row] - CMARGIN && lamf[sm][r] >= cthr) {
                    if (p < CAND_CAP) {
                        cidx[p] = ((uint32)n << 24) | ((uint32)(tM * 128 + row) << 12) | colG;
                        ct[p] = ((u64)(uint32)t01v[sm][r] << 32) | (u64)(uint32)t23v[sm][r];
                    }
                    p++;
                }
            }
    }
}

__global__ __launch_bounds__(256) void merge_kernel(
    const float* __restrict__ rpf, const float* __restrict__ cpf,
    double* __restrict__ lse_row, double* __restrict__ lse_col)
{
    int idx = blockIdx.x * 256 + threadIdx.x;
    const float* src = (idx < BATCH * LDIM) ? rpf : cpf;
    double* dst = (idx < BATCH * LDIM) ? lse_row : lse_col;
    int i = idx & (BATCH * LDIM - 1);
    float M = -3.4e38f;
#pragma unroll
    for (int j = 0; j < 32; j++) M = fmaxf(M, src[(size_t)i * 32 + j]);
    double S = 0.0;
#pragma unroll
    for (int j = 0; j < 32; j++)
        S += exp2((double)src[(size_t)i * 32 + j] - (double)M);
    dst[i] = (double)M + log2(S);
}

// Exact keys for candidates only; identical gf arithmetic to the fallback.
__global__ __launch_bounds__(256) void finalize_kernel(
    const uint32* __restrict__ cidx, const u64* __restrict__ ct,
    const uint32* __restrict__ ccount,
    const double* __restrict__ lse_row, const double* __restrict__ lse_col,
    u64* __restrict__ rowpack, u64* __restrict__ colpack)
{
    uint32 cnt = ccount[0];
    if (cnt > CAND_CAP) cnt = CAND_CAP;
    uint32 i = blockIdx.x * 256 + threadIdx.x;
    if (i >= cnt) return;
    uint32 id = cidx[i];
    int n = id >> 24, rowG = (id >> 12) & 4095, colG = id & 4095;
    u64 tt = ct[i];
    int t01 = (int)(uint32)(tt >> 32), t23 = (int)(uint32)tt;
    double l2 = (double)t01 * C1L + (double)t23 * C2L;
    float gf = (float)(2.0 * l2 - lse_row[(size_t)n * LDIM + rowG]
                                - lse_col[(size_t)n * LDIM + colG]);
    u64 key = ((u64)fkey(gf)) << 32;
    atomicMax(&rowpack[(size_t)n * LDIM + rowG], key | (uint32)(~(uint32)colG));
    atomicMax(&colpack[(size_t)n * LDIM + colG], key | (uint32)(~(uint32)rowG));
}

// Overflow fallback (round-7 PASS2): full recompute with t01 filter.
// Early-exits unless the candidate buffer overflowed.
__global__ __launch_bounds__(512, 2) void gemm_fallback(
    const char* __restrict__ dig, const uint32* __restrict__ ccount,
    const double* __restrict__ lse_row, const double* __restrict__ lse_col,
    u64* __restrict__ rowpack, u64* __restrict__ colpack)
{
    if (ccount[0] <= CAND_CAP) return;

    __shared__ __align__(16) char smp[68608];
    int wg = blockIdx.x;
    int swz = (wg & 7) * 1024 + (wg >> 3);
    int n  = swz >> 10;
    int tM = (swz >> 5) & 31;
    int tN = swz & 31;

    const int t = threadIdx.x;
    const int lane = t & 63, w = t >> 6;
    const int wr = w >> 2, wc = w & 3;
    const int l31 = lane & 31, kg = lane >> 5;

    double* lserd = (double*)(smp + 65536);
    // layout: lserd[128]@65536, lsecd[128]@66560, lserf[128]@67584, lsecf[128]@68096
    double* lsecd = (double*)(smp + 66560);
    float*  lserf = (float*)(smp + 67584);
    float*  lsecf = (float*)(smp + 68096);
    if (t < 128) {
        double d = lse_row[(size_t)n * LDIM + tM * 128 + t];
        lserd[t] = d; lserf[t] = (float)d;
    } else if (t < 256) {
        int c = t - 128;
        double d = lse_col[(size_t)n * LDIM + tN * 128 + c];
        lsecd[c] = d; lsecf[c] = (float)d;
    }

    const i32x16 zero16 = {0,0,0,0,0,0,0,0,0,0,0,0,0,0,0,0};
    i32x16 acc[2][4];
#pragma unroll
    for (int sm = 0; sm < 2; sm++)
#pragma unroll
        for (int k = 0; k < 4; k++) acc[sm][k] = zero16;

    auto stage_step = [&](int kc, int buf) {
#pragma unroll
        for (int i = 0; i < 4; i++) {
            int blk = (i < 2) ? (tM * 2 + i) : (tN * 2 + (i - 2));
            const char* src = dig + ((i < 2) ? DIG1_OFF : DIG2_OFF)
                            + (((size_t)n * 64 + blk) * 4 + kc) * 8192 + t * 16;
            load_lds16(src, smp + buf * 32768 + i * 8192 + t * 16);
        }
    };

    stage_step(0, 0);
    for (int kc = 0; kc < 4; kc++) {
        int buf = kc & 1;
        __syncthreads();
        if (kc < 3) stage_step(kc + 1, buf ^ 1);
        const char* Ab = smp + buf * 32768 + wr * 8192;
        const char* Bb = smp + buf * 32768 + 16384 + (wc >> 1) * 8192 + (wc & 1) * 1024;
        i32x4 aF[2][4], bF[4];
#pragma unroll
        for (int p = 0; p < 4; p++)
            bF[p] = *(const i32x4*)(Bb + p * 2048 + lane * 16);
#pragma unroll
        for (int sm = 0; sm < 2; sm++)
#pragma unroll
            for (int p = 0; p < 4; p++)
                aF[sm][p] = *(const i32x4*)(Ab + p * 2048 + sm * 1024 + lane * 16);
#pragma unroll
        for (int sm = 0; sm < 2; sm++) {
            acc[sm][0] = mfma_i8(aF[sm][0], bF[0], acc[sm][0]);
            acc[sm][1] = mfma_i8(aF[sm][0], bF[1], acc[sm][1]);
            acc[sm][1] = mfma_i8(aF[sm][1], bF[0], acc[sm][1]);
            acc[sm][2] = mfma_i8(aF[sm][0], bF[2], acc[sm][2]);
            acc[sm][2] = mfma_i8(aF[sm][1], bF[1], acc[sm][2]);
            acc[sm][2] = mfma_i8(aF[sm][2], bF[0], acc[sm][2]);
            acc[sm][3] = mfma_i8(aF[sm][0], bF[3], acc[sm][3]);
            acc[sm][3] = mfma_i8(aF[sm][1], bF[2], acc[sm][3]);
            acc[sm][3] = mfma_i8(aF[sm][2], bF[1], acc[sm][3]);
            acc[sm][3] = mfma_i8(aF[sm][3], bF[0], acc[sm][3]);
        }
    }
    __syncthreads();

    const int col = wc * 32 + l31;
    const float two_c1f = (float)(2.0 * C1L);
    const float scol = lsecf[col] + (float)LOG2_02 - 17.0f;
    const double lcd = lsecd[col];
#pragma unroll
    for (int sm = 0; sm < 2; sm++)
#pragma unroll
        for (int r = 0; r < 16; r++) {
            int row = wr * 64 + sm * 32 + CROW(r, kg);
            int t01 = acc[sm][0][r] * 128 + acc[sm][1][r];
            float lv = (float)t01 * two_c1f;
            if (lv > lserf[row] + scol) {
                int t23 = acc[sm][2][r] * 128 + acc[sm][3][r];
                double l2 = (double)t01 * C1L + (double)t23 * C2L;
                float gf = (float)(2.0 * l2 - lserd[row] - lcd);
                u64 key = ((u64)fkey(gf)) << 32;
                atomicMax(&rowpack[(size_t)n * LDIM + tM * 128 + row],
                          key | (uint32)(~(uint32)(tN * 128 + col)));
                atomicMax(&colpack[(size_t)n * LDIM + tN * 128 + col],
                          key | (uint32)(~(uint32)(tM * 128 + row)));
            }
        }
}

__global__ __launch_bounds__(256) void out_kernel(
    const float* __restrict__ f1, const float* __restrict__ f2,
    const u64* __restrict__ rowpack, const u64* __restrict__ colpack,
    float* __restrict__ out)
{
    int n = blockIdx.y;
    int l0 = blockIdx.x * 64;
    int t = threadIdx.x;
    __shared__ int s_sh[64];
    __shared__ int m_sh[64];
    __shared__ float tile[64][129];
    if (t < 64) {
        u64 rp = rowpack[(size_t)n * LDIM + l0 + t];
        uint32 skey = (uint32)(rp >> 32);
        uint32 s = (~(uint32)rp) & 4095u;
        u64 cp = colpack[(size_t)n * LDIM + s];
        double g2 = (double)keyf(skey);
        int match = (((uint32)(cp >> 32)) == skey) && (g2 > LOG2_02);
        s_sh[t] = (int)s;
        m_sh[t] = match;
    }
    __syncthreads();
#pragma unroll
    for (int i = 0; i < 32; i++) {
        int idx = i * 256 + t;
        int lloc = idx >> 7, ch = idx & 127;
        float v = f1[((size_t)n * LDIM + l0 + lloc) * CDIM + ch];
        if (m_sh[lloc]) v -= f2[((size_t)n * LDIM + s_sh[lloc]) * CDIM + ch];
        tile[lloc][ch] = v;
    }
    __syncthreads();
#pragma unroll
    for (int i = 0; i < 32; i++) {
        int ch = i * 4 + (t >> 6), lw = t & 63;
        out[((size_t)n * CDIM + ch) * LDIM + l0 + lw] = tile[lw][ch];
    }
}

extern "C" void kernel_launch(void* const* d_in, const int* in_sizes, int n_in,
                              void* d_out, int out_size, void* d_ws, size_t ws_size,
                              hipStream_t stream)
{
    const float* f1 = (const float*)d_in[0];
    const float* f2 = (const float*)d_in[1];
    float* out = (float*)d_out;
    char* ws = (char*)d_ws;
    char* dig = ws;

    if (ws_size < WS_NEEDED) {
        fill_sentinel<<<(out_size + 255) / 256, 256, 0, stream>>>(out, out_size);
        return;
    }

    float* rpf      = (float*)(ws + RPF_OFF);
    float* cpf      = (float*)(ws + CPF_OFF);
    double* lse_row = (double*)(ws + LSER_OFF);
    double* lse_col = (double*)(ws + LSEC_OFF);
    u64* rowpack    = (u64*)(ws + RPACK_OFF);
    u64* colpack    = (u64*)(ws + CPACK_OFF);
    uint32* ccount  = (uint32*)(ws + CCNT_OFF);
    uint32* cidx    = (uint32*)(ws + CIDX_OFF);
    u64* ct         = (u64*)(ws + CT_OFF);

    quant_kernel<<<dim3(2048), dim3(256), 0, stream>>>(f1, f2, dig);
    init_packs<<<dim3(128), dim3(256), 0, stream>>>(rowpack, colpack, ccount);
    gemm_fused<<<dim3(8192), dim3(512), 0, stream>>>(dig, rpf, cpf, ccount, cidx, ct);
    merge_kernel<<<dim3(256), dim3(256), 0, stream>>>(rpf, cpf, lse_row, lse_col);
    finalize_kernel<<<dim3((CAND_CAP + 255) / 256), dim3(256), 0, stream>>>(
        cidx, ct, ccount, lse_row, lse_col, rowpack, colpack);
    gemm_fallback<<<dim3(8192), dim3(512), 0, stream>>>(
        dig, ccount, lse_row, lse_col, rowpack, colpack);
    out_kernel<<<dim3(LDIM / 64, BATCH), dim3(256), 0, stream>>>(
        f1, f2, rowpack, colpack, out);
}

// Round 11
// 404.349 us; speedup vs baseline: 1.4258x; 1.1059x over previous
//
#include <hip/hip_runtime.h>
#include <stdint.h>

typedef unsigned int uint32;
typedef unsigned long long u64;

#define BATCH 8
#define LDIM 4096
#define CDIM 128

typedef __attribute__((ext_vector_type(4))) int i32x4;
typedef __attribute__((ext_vector_type(16))) int i32x16;

// ---- workspace layout (bytes) ----
#define DIG1_OFF  0ull           /* i8 digits f1, LDS-order: 16 MB */
#define DIG2_OFF  16777216ull    /* i8 digits f2 */
#define RPF_OFF   33554432ull    /* float [8][4096][32] partial row LSE, 4 MB */
#define CPF_OFF   37748736ull    /* float [8][4096][32] partial col LSE, 4 MB */
#define LSER_OFF  41943040ull    /* double [8][4096] */
#define LSEC_OFF  42205184ull
#define RPACK_OFF 42467328ull    /* u64 [8][4096] */
#define CPACK_OFF 42729472ull
#define CCNT_OFF  42991616ull    /* u32 counter (+pad) */
#define CIDX_OFF  42995712ull    /* u32 [CAND_CAP] */
#define CT_OFF    45755712ull    /* u64 [CAND_CAP] */
#define WS_NEEDED 51380224ull    /* layout ends 51,275,712 */

#define CAND_CAP 690000u
#define CMARGIN 2.40f

// lam2 = log2(e) * 10 * (t01*2^-15 + t23*2^-29)  (log2-domain logits)
#define C1L (3.0517578125e-04 * 1.4426950408889634)
#define C2L (1.862645149230957e-08 * 1.4426950408889634)
#define LOG2_02 (-2.3219280948873623)   /* log2(0.2) */

#define CROW(r, kgv) (((r)&3) + 8*((r)>>2) + 4*(kgv))

__device__ __forceinline__ uint32 fkey(float f) {
    uint32 u = __float_as_uint(f);
    return (u & 0x80000000u) ? ~u : (u | 0x80000000u);
}
__device__ __forceinline__ float keyf(uint32 k) {
    uint32 u = (k & 0x80000000u) ? (k ^ 0x80000000u) : ~k;
    return __uint_as_float(u);
}
__device__ __forceinline__ i32x16 mfma_i8(i32x4 a, i32x4 b, i32x16 c) {
    return __builtin_amdgcn_mfma_i32_32x32x32_i8(a, b, c, 0, 0, 0);
}
__device__ __forceinline__ void load_lds16(const char* g, char* l) {
    __builtin_amdgcn_global_load_lds((__attribute__((address_space(1))) void*)(g),
                                     (__attribute__((address_space(3))) void*)(l), 16, 0, 0);
}
__device__ __forceinline__ u64 umax64(u64 a, u64 b) { return a > b ? a : b; }

__global__ void fill_sentinel(float* out, int nelem) {
    int i = blockIdx.x * 256 + threadIdx.x;
    if (i < nelem) out[i] = 12345.0f;
}

__global__ void init_packs(u64* __restrict__ rowpack, u64* __restrict__ colpack,
                           uint32* __restrict__ ccount) {
    int idx = blockIdx.x * 256 + threadIdx.x;
    if (idx < BATCH * LDIM) { rowpack[idx] = 0ull; colpack[idx] = 0ull; }
    if (idx == 0) ccount[0] = 0u;
}

// Quantize fp32 -> 4 exact base-128 signed digits of round(x*2^25).
__global__ __launch_bounds__(256) void quant_kernel(const float* __restrict__ f1,
                                                    const float* __restrict__ f2,
                                                    char* __restrict__ dig)
{
    int tid = blockIdx.x * 256 + threadIdx.x;
    int l31 = tid & 31;
    int kg  = (tid >> 5) & 1;
    int kc  = (tid >> 6) & 3;
    int rb  = (tid >> 8) & 1;
    int blk = (tid >> 9) & 63;
    int n   = (tid >> 15) & 7;
    int inp = tid >> 18;
    int row = blk * 64 + rb * 32 + l31;

    const float* src = (inp ? f2 : f1) + ((size_t)(n * LDIM + row)) * CDIM + kc * 32 + kg * 16;
    char* dstc = dig + (inp ? DIG2_OFF : DIG1_OFF)
               + (((size_t)n * 64 + blk) * 4 + kc) * 8192;
    int gpos = rb * 64 + kg * 32 + l31;

    float4 v0 = ((const float4*)src)[0];
    float4 v1 = ((const float4*)src)[1];
    float4 v2 = ((const float4*)src)[2];
    float4 v3 = ((const float4*)src)[3];
    float xs[16] = {v0.x,v0.y,v0.z,v0.w, v1.x,v1.y,v1.z,v1.w,
                    v2.x,v2.y,v2.z,v2.w, v3.x,v3.y,v3.z,v3.w};
    uint32 wds[4][4] = {{0,0,0,0},{0,0,0,0},{0,0,0,0},{0,0,0,0}};
#pragma unroll
    for (int e = 0; e < 16; e++) {
        int q = __float2int_rn(xs[e] * 33554432.0f);
        int d0 = (q + (1 << 20)) >> 21; q -= d0 << 21;
        int d1 = (q + (1 << 13)) >> 14; q -= d1 << 14;
        int d2 = (q + (1 << 6)) >> 7;   q -= d2 << 7;
        int sh = (e & 3) * 8;
        wds[0][e >> 2] |= (uint32)(d0 & 255) << sh;
        wds[1][e >> 2] |= (uint32)(d1 & 255) << sh;
        wds[2][e >> 2] |= (uint32)(d2 & 255) << sh;
        wds[3][e >> 2] |= (uint32)(q  & 255) << sh;
    }
#pragma unroll
    for (int p = 0; p < 4; p++) {
        *(int4*)(dstc + (size_t)(p * 128 + gpos) * 16) =
            make_int4(wds[p][0], wds[p][1], wds[p][2], wds[p][3]);
    }
}

// FUSED single GEMM pass: exact i8-digit products -> fp32 stats partials
// (log2 LSE per tile) + candidate emission (elements within CMARGIN bits of
// BOTH tile row max and tile col max; superset of all m>0.2 elements).
__global__ __launch_bounds__(512, 2) void gemm_fused(
    const char* __restrict__ dig,
    float* __restrict__ rpf, float* __restrict__ cpf,
    uint32* __restrict__ ccount, uint32* __restrict__ cidx, u64* __restrict__ ct)
{
    __shared__ __align__(16) char smp[75840];
    // stage: 2 bufs x 32KB @0..65536
    // epilogue reuse: trf f32[128][129] @0 (66048), rstat f2[4][128] @66560,
    // cpart f2[4][128] @70656, rowMaxF[128] @74752, colMaxF[128] @75264,
    // waveTot u32[9] @75776

    int wg = blockIdx.x;
    int swz = (wg & 7) * 1024 + (wg >> 3);    // one batch per XCD
    int n  = swz >> 10;
    int tM = (swz >> 5) & 31;
    int tN = swz & 31;

    const int t = threadIdx.x;
    const int lane = t & 63, w = t >> 6;
    const int wr = w >> 2, wc = w & 3;
    const int l31 = lane & 31, kg = lane >> 5;

    const i32x16 zero16 = {0,0,0,0,0,0,0,0,0,0,0,0,0,0,0,0};
    i32x16 acc[2][4];
#pragma unroll
    for (int sm = 0; sm < 2; sm++)
#pragma unroll
        for (int k = 0; k < 4; k++) acc[sm][k] = zero16;

    auto stage_step = [&](int kc, int buf) {
#pragma unroll
        for (int i = 0; i < 4; i++) {
            int blk = (i < 2) ? (tM * 2 + i) : (tN * 2 + (i - 2));
            const char* src = dig + ((i < 2) ? DIG1_OFF : DIG2_OFF)
                            + (((size_t)n * 64 + blk) * 4 + kc) * 8192 + t * 16;
            load_lds16(src, smp + buf * 32768 + i * 8192 + t * 16);
        }
    };

    stage_step(0, 0);
    for (int kc = 0; kc < 4; kc++) {
        int buf = kc & 1;
        __syncthreads();
        if (kc < 3) stage_step(kc + 1, buf ^ 1);
        const char* Ab = smp + buf * 32768 + wr * 8192;
        const char* Bb = smp + buf * 32768 + 16384 + (wc >> 1) * 8192 + (wc & 1) * 1024;
        i32x4 aF[2][4], bF[4];
#pragma unroll
        for (int p = 0; p < 4; p++)
            bF[p] = *(const i32x4*)(Bb + p * 2048 + lane * 16);
#pragma unroll
        for (int sm = 0; sm < 2; sm++)
#pragma unroll
            for (int p = 0; p < 4; p++)
                aF[sm][p] = *(const i32x4*)(Ab + p * 2048 + sm * 1024 + lane * 16);
#pragma unroll
        for (int sm = 0; sm < 2; sm++) {
            acc[sm][0] = mfma_i8(aF[sm][0], bF[0], acc[sm][0]);   // T0
            acc[sm][1] = mfma_i8(aF[sm][0], bF[1], acc[sm][1]);   // T1
            acc[sm][1] = mfma_i8(aF[sm][1], bF[0], acc[sm][1]);
            acc[sm][2] = mfma_i8(aF[sm][0], bF[2], acc[sm][2]);   // T2
            acc[sm][2] = mfma_i8(aF[sm][1], bF[1], acc[sm][2]);
            acc[sm][2] = mfma_i8(aF[sm][2], bF[0], acc[sm][2]);
            acc[sm][3] = mfma_i8(aF[sm][0], bF[3], acc[sm][3]);   // T3
            acc[sm][3] = mfma_i8(aF[sm][1], bF[2], acc[sm][3]);
            acc[sm][3] = mfma_i8(aF[sm][2], bF[1], acc[sm][3]);
            acc[sm][3] = mfma_i8(aF[sm][3], bF[0], acc[sm][3]);
        }
    }

    const int col = wc * 32 + l31;

    // exact integer pairs (kept live for emission) + fp32 logits for stats
    int t01v[2][16], t23v[2][16];
    float lamf[2][16];
    const float c1f = (float)C1L, c2f = (float)C2L;
#pragma unroll
    for (int sm = 0; sm < 2; sm++)
#pragma unroll
        for (int r = 0; r < 16; r++) {
            t01v[sm][r] = acc[sm][0][r] * 128 + acc[sm][1][r];
            t23v[sm][r] = acc[sm][2][r] * 128 + acc[sm][3][r];
            lamf[sm][r] = fmaf((float)t23v[sm][r], c2f, (float)t01v[sm][r] * c1f);
        }

    float* trf = (float*)smp;                       // [128][129]
    float2* rstat = (float2*)(smp + 66560);         // [4][128]
    float2* cpart = (float2*)(smp + 70656);         // [4][128]
    float* rowMaxF = (float*)(smp + 74752);         // [128]
    float* colMaxF = (float*)(smp + 75264);         // [128]
    uint32* waveTot = (uint32*)(smp + 75776);       // [9]: 8 wave bases + blkBase

    __syncthreads();   // all frag reads done; stage region reusable

    // ---- phase A: transpose write + col partials ----
#pragma unroll
    for (int sm = 0; sm < 2; sm++)
#pragma unroll
        for (int r = 0; r < 16; r++) {
            int row = wr * 64 + sm * 32 + CROW(r, kg);
            trf[row * 129 + col] = lamf[sm][r];
        }
    {
        float cm = lamf[0][0];
#pragma unroll
        for (int sm = 0; sm < 2; sm++)
#pragma unroll
            for (int r = 0; r < 16; r++) cm = fmaxf(cm, lamf[sm][r]);
        float cs = 0.f;
#pragma unroll
        for (int sm = 0; sm < 2; sm++)
#pragma unroll
            for (int r = 0; r < 16; r++) cs += exp2f(lamf[sm][r] - cm);
        cpart[(wr * 2 + kg) * 128 + col] = make_float2(cm, cs);
    }
    __syncthreads();

    // ---- phase B: per-segment row stats (transpose read) ----
    {
        int row = t & 127, seg = t >> 7;
        const float* rp = trf + row * 129 + seg * 32;
        float v[32];
#pragma unroll
        for (int j = 0; j < 32; j++) v[j] = rp[j];
        float rm = v[0];
#pragma unroll
        for (int j = 1; j < 32; j++) rm = fmaxf(rm, v[j]);
        float rs = 0.f;
#pragma unroll
        for (int j = 0; j < 32; j++) rs += exp2f(v[j] - rm);
        rstat[seg * 128 + row] = make_float2(rm, rs);
    }
    __syncthreads();

    // ---- phase B2: merges + maxima publish + partial stores ----
    if (t < 128) {
        float2 a = rstat[t], b = rstat[128 + t], c = rstat[256 + t], d = rstat[384 + t];
        float M = fmaxf(fmaxf(a.x, b.x), fmaxf(c.x, d.x));
        float S = a.y * exp2f(a.x - M) + b.y * exp2f(b.x - M)
                + c.y * exp2f(c.x - M) + d.y * exp2f(d.x - M);
        rowMaxF[t] = M;
        rpf[((size_t)n * LDIM + tM * 128 + t) * 32 + tN] = M + log2f(S);
    } else if (t < 256) {
        int c0 = t - 128;
        float2 a = cpart[c0], b = cpart[128 + c0], c = cpart[256 + c0], d = cpart[384 + c0];
        float M = fmaxf(fmaxf(a.x, b.x), fmaxf(c.x, d.x));
        float S = a.y * exp2f(a.x - M) + b.y * exp2f(b.x - M)
                + c.y * exp2f(c.x - M) + d.y * exp2f(d.x - M);
        colMaxF[c0] = M;
        cpf[((size_t)n * LDIM + tN * 128 + c0) * 32 + tM] = M + log2f(S);
    }
    __syncthreads();   // maxima ready

    // ---- phase C: candidate scan, ONE evaluation -> bitmask ----
    uint32 mask = 0;
    {
        const float cthr = colMaxF[col] - CMARGIN;
#pragma unroll
        for (int sm = 0; sm < 2; sm++)
#pragma unroll
            for (int r = 0; r < 16; r++) {
                int row = wr * 64 + sm * 32 + CROW(r, kg);
                if (lamf[sm][r] >= rowMaxF[row] - CMARGIN && lamf[sm][r] >= cthr)
                    mask |= 1u << (sm * 16 + r);
            }
    }
    uint32 cnt = (uint32)__popc(mask);
    uint32 x = cnt;
#pragma unroll
    for (int d = 1; d < 64; d <<= 1) {
        uint32 y = __shfl_up(x, d);
        if (lane >= d) x += y;
    }
    if (lane == 63) waveTot[w] = x;
    __syncthreads();
    if (t == 0) {
        uint32 s = 0;
#pragma unroll
        for (int i = 0; i < 8; i++) { uint32 v = waveTot[i]; waveTot[i] = s; s += v; }
        waveTot[8] = s ? atomicAdd(ccount, s) : 0u;
    }
    __syncthreads();

    // ---- phase E: emission (static-indexed, mask-gated) ----
    if (mask) {
        uint32 p = waveTot[8] + waveTot[w] + (x - cnt);
        const uint32 colG = (uint32)(tN * 128 + col);
#pragma unroll
        for (int sm = 0; sm < 2; sm++)
#pragma unroll
            for (int r = 0; r < 16; r++) {
                if (mask & (1u << (sm * 16 + r))) {
                    int row = wr * 64 + sm * 32 + CROW(r, kg);
                    if (p < CAND_CAP) {
                        cidx[p] = ((uint32)n << 24) | ((uint32)(tM * 128 + row) << 12) | colG;
                        ct[p] = ((u64)(uint32)t01v[sm][r] << 32) | (u64)(uint32)t23v[sm][r];
                    }
                    p++;
                }
            }
    }
}

__global__ __launch_bounds__(256) void merge_kernel(
    const float* __restrict__ rpf, const float* __restrict__ cpf,
    double* __restrict__ lse_row, double* __restrict__ lse_col)
{
    int idx = blockIdx.x * 256 + threadIdx.x;
    const float* src = (idx < BATCH * LDIM) ? rpf : cpf;
    double* dst = (idx < BATCH * LDIM) ? lse_row : lse_col;
    int i = idx & (BATCH * LDIM - 1);
    float M = -3.4e38f;
#pragma unroll
    for (int j = 0; j < 32; j++) M = fmaxf(M, src[(size_t)i * 32 + j]);
    double S = 0.0;
#pragma unroll
    for (int j = 0; j < 32; j++)
        S += exp2((double)src[(size_t)i * 32 + j] - (double)M);
    dst[i] = (double)M + log2(S);
}

// Exact keys for candidates only; identical gf arithmetic to the fallback.
__global__ __launch_bounds__(256) void finalize_kernel(
    const uint32* __restrict__ cidx, const u64* __restrict__ ct,
    const uint32* __restrict__ ccount,
    const double* __restrict__ lse_row, const double* __restrict__ lse_col,
    u64* __restrict__ rowpack, u64* __restrict__ colpack)
{
    uint32 cnt = ccount[0];
    if (cnt > CAND_CAP) cnt = CAND_CAP;
    uint32 i = blockIdx.x * 256 + threadIdx.x;
    if (i >= cnt) return;
    uint32 id = cidx[i];
    int n = id >> 24, rowG = (id >> 12) & 4095, colG = id & 4095;
    u64 tt = ct[i];
    int t01 = (int)(uint32)(tt >> 32), t23 = (int)(uint32)tt;
    double l2 = (double)t01 * C1L + (double)t23 * C2L;
    float gf = (float)(2.0 * l2 - lse_row[(size_t)n * LDIM + rowG]
                                - lse_col[(size_t)n * LDIM + colG]);
    u64 key = ((u64)fkey(gf)) << 32;
    atomicMax(&rowpack[(size_t)n * LDIM + rowG], key | (uint32)(~(uint32)colG));
    atomicMax(&colpack[(size_t)n * LDIM + colG], key | (uint32)(~(uint32)rowG));
}

// Overflow fallback (round-7 PASS2): full recompute with t01 filter.
// Early-exits unless the candidate buffer overflowed.
__global__ __launch_bounds__(512, 2) void gemm_fallback(
    const char* __restrict__ dig, const uint32* __restrict__ ccount,
    const double* __restrict__ lse_row, const double* __restrict__ lse_col,
    u64* __restrict__ rowpack, u64* __restrict__ colpack)
{
    if (ccount[0] <= CAND_CAP) return;

    __shared__ __align__(16) char smp[68608];
    int wg = blockIdx.x;
    int swz = (wg & 7) * 1024 + (wg >> 3);
    int n  = swz >> 10;
    int tM = (swz >> 5) & 31;
    int tN = swz & 31;

    const int t = threadIdx.x;
    const int lane = t & 63, w = t >> 6;
    const int wr = w >> 2, wc = w & 3;
    const int l31 = lane & 31, kg = lane >> 5;

    double* lserd = (double*)(smp + 65536);
    double* lsecd = (double*)(smp + 66560);
    float*  lserf = (float*)(smp + 67584);
    float*  lsecf = (float*)(smp + 68096);
    if (t < 128) {
        double d = lse_row[(size_t)n * LDIM + tM * 128 + t];
        lserd[t] = d; lserf[t] = (float)d;
    } else if (t < 256) {
        int c = t - 128;
        double d = lse_col[(size_t)n * LDIM + tN * 128 + c];
        lsecd[c] = d; lsecf[c] = (float)d;
    }

    const i32x16 zero16 = {0,0,0,0,0,0,0,0,0,0,0,0,0,0,0,0};
    i32x16 acc[2][4];
#pragma unroll
    for (int sm = 0; sm < 2; sm++)
#pragma unroll
        for (int k = 0; k < 4; k++) acc[sm][k] = zero16;

    auto stage_step = [&](int kc, int buf) {
#pragma unroll
        for (int i = 0; i < 4; i++) {
            int blk = (i < 2) ? (tM * 2 + i) : (tN * 2 + (i - 2));
            const char* src = dig + ((i < 2) ? DIG1_OFF : DIG2_OFF)
                            + (((size_t)n * 64 + blk) * 4 + kc) * 8192 + t * 16;
            load_lds16(src, smp + buf * 32768 + i * 8192 + t * 16);
        }
    };

    stage_step(0, 0);
    for (int kc = 0; kc < 4; kc++) {
        int buf = kc & 1;
        __syncthreads();
        if (kc < 3) stage_step(kc + 1, buf ^ 1);
        const char* Ab = smp + buf * 32768 + wr * 8192;
        const char* Bb = smp + buf * 32768 + 16384 + (wc >> 1) * 8192 + (wc & 1) * 1024;
        i32x4 aF[2][4], bF[4];
#pragma unroll
        for (int p = 0; p < 4; p++)
            bF[p] = *(const i32x4*)(Bb + p * 2048 + lane * 16);
#pragma unroll
        for (int sm = 0; sm < 2; sm++)
#pragma unroll
            for (int p = 0; p < 4; p++)
                aF[sm][p] = *(const i32x4*)(Ab + p * 2048 + sm * 1024 + lane * 16);
#pragma unroll
        for (int sm = 0; sm < 2; sm++) {
            acc[sm][0] = mfma_i8(aF[sm][0], bF[0], acc[sm][0]);
            acc[sm][1] = mfma_i8(aF[sm][0], bF[1], acc[sm][1]);
            acc[sm][1] = mfma_i8(aF[sm][1], bF[0], acc[sm][1]);
            acc[sm][2] = mfma_i8(aF[sm][0], bF[2], acc[sm][2]);
            acc[sm][2] = mfma_i8(aF[sm][1], bF[1], acc[sm][2]);
            acc[sm][2] = mfma_i8(aF[sm][2], bF[0], acc[sm][2]);
            acc[sm][3] = mfma_i8(aF[sm][0], bF[3], acc[sm][3]);
            acc[sm][3] = mfma_i8(aF[sm][1], bF[2], acc[sm][3]);
            acc[sm][3] = mfma_i8(aF[sm][2], bF[1], acc[sm][3]);
            acc[sm][3] = mfma_i8(aF[sm][3], bF[0], acc[sm][3]);
        }
    }
    __syncthreads();

    const int col = wc * 32 + l31;
    const float two_c1f = (float)(2.0 * C1L);
    const float scol = lsecf[col] + (float)LOG2_02 - 17.0f;
    const double lcd = lsecd[col];
#pragma unroll
    for (int sm = 0; sm < 2; sm++)
#pragma unroll
        for (int r = 0; r < 16; r++) {
            int row = wr * 64 + sm * 32 + CROW(r, kg);
            int t01 = acc[sm][0][r] * 128 + acc[sm][1][r];
            float lv = (float)t01 * two_c1f;
            if (lv > lserf[row] + scol) {
                int t23 = acc[sm][2][r] * 128 + acc[sm][3][r];
                double l2 = (double)t01 * C1L + (double)t23 * C2L;
                float gf = (float)(2.0 * l2 - lserd[row] - lcd);
                u64 key = ((u64)fkey(gf)) << 32;
                atomicMax(&rowpack[(size_t)n * LDIM + tM * 128 + row],
                          key | (uint32)(~(uint32)(tN * 128 + col)));
                atomicMax(&colpack[(size_t)n * LDIM + tN * 128 + col],
                          key | (uint32)(~(uint32)(tM * 128 + row)));
            }
        }
}

__global__ __launch_bounds__(256) void out_kernel(
    const float* __restrict__ f1, const float* __restrict__ f2,
    const u64* __restrict__ rowpack, const u64* __restrict__ colpack,
    float* __restrict__ out)
{
    int n = blockIdx.y;
    int l0 = blockIdx.x * 64;
    int t = threadIdx.x;
    __shared__ int s_sh[64];
    __shared__ int m_sh[64];
    __shared__ float tile[64][129];
    if (t < 64) {
        u64 rp = rowpack[(size_t)n * LDIM + l0 + t];
        uint32 skey = (uint32)(rp >> 32);
        uint32 s = (~(uint32)rp) & 4095u;
        u64 cp = colpack[(size_t)n * LDIM + s];
        double g2 = (double)keyf(skey);
        int match = (((uint32)(cp >> 32)) == skey) && (g2 > LOG2_02);
        s_sh[t] = (int)s;
        m_sh[t] = match;
    }
    __syncthreads();
#pragma unroll
    for (int i = 0; i < 32; i++) {
        int idx = i * 256 + t;
        int lloc = idx >> 7, ch = idx & 127;
        float v = f1[((size_t)n * LDIM + l0 + lloc) * CDIM + ch];
        if (m_sh[lloc]) v -= f2[((size_t)n * LDIM + s_sh[lloc]) * CDIM + ch];
        tile[lloc][ch] = v;
    }
    __syncthreads();
#pragma unroll
    for (int i = 0; i < 32; i++) {
        int ch = i * 4 + (t >> 6), lw = t & 63;
        out[((size_t)n * CDIM + ch) * LDIM + l0 + lw] = tile[lw][ch];
    }
}

extern "C" void kernel_launch(void* const* d_in, const int* in_sizes, int n_in,
                              void* d_out, int out_size, void* d_ws, size_t ws_size,
                              hipStream_t stream)
{
    const float* f1 = (const float*)d_in[0];
    const float* f2 = (const float*)d_in[1];
    float* out = (float*)d_out;
    char* ws = (char*)d_ws;
    char* dig = ws;

    if (ws_size < WS_NEEDED) {
        fill_sentinel<<<(out_size + 255) / 256, 256, 0, stream>>>(out, out_size);
        return;
    }

    float* rpf      = (float*)(ws + RPF_OFF);
    float* cpf      = (float*)(ws + CPF_OFF);
    double* lse_row = (double*)(ws + LSER_OFF);
    double* lse_col = (double*)(ws + LSEC_OFF);
    u64* rowpack    = (u64*)(ws + RPACK_OFF);
    u64* colpack    = (u64*)(ws + CPACK_OFF);
    uint32* ccount  = (uint32*)(ws + CCNT_OFF);
    uint32* cidx    = (uint32*)(ws + CIDX_OFF);
    u64* ct         = (u64*)(ws + CT_OFF);

    quant_kernel<<<dim3(2048), dim3(256), 0, stream>>>(f1, f2, dig);
    init_packs<<<dim3(128), dim3(256), 0, stream>>>(rowpack, colpack, ccount);
    gemm_fused<<<dim3(8192), dim3(512), 0, stream>>>(dig, rpf, cpf, ccount, cidx, ct);
    merge_kernel<<<dim3(256), dim3(256), 0, stream>>>(rpf, cpf, lse_row, lse_col);
    finalize_kernel<<<dim3((CAND_CAP + 255) / 256), dim3(256), 0, stream>>>(
        cidx, ct, ccount, lse_row, lse_col, rowpack, colpack);
    gemm_fallback<<<dim3(8192), dim3(512), 0, stream>>>(
        dig, ccount, lse_row, lse_col, rowpack, colpack);
    out_kernel<<<dim3(LDIM / 64, BATCH), dim3(256), 0, stream>>>(
        f1, f2, rowpack, colpack, out);
}

// Round 12
// 371.291 us; speedup vs baseline: 1.5528x; 1.0890x over previous
//
#include <hip/hip_runtime.h>
#include <stdint.h>

typedef unsigned int uint32;
typedef unsigned long long u64;

#define BATCH 8
#define LDIM 4096
#define CDIM 128

typedef __attribute__((ext_vector_type(4))) int i32x4;
typedef __attribute__((ext_vector_type(16))) int i32x16;

// ---- workspace layout (bytes) ----
#define DIG1_OFF  0ull           /* i8 digits f1, LDS-order: 16 MB */
#define DIG2_OFF  16777216ull    /* i8 digits f2 */
#define RPF_OFF   33554432ull    /* float [8][4096][32] partial row LSE, 4 MB */
#define CPF_OFF   37748736ull    /* float [8][4096][32] partial col LSE, 4 MB */
#define LSER_OFF  41943040ull    /* double [8][4096] */
#define LSEC_OFF  42205184ull
#define RPACK_OFF 42467328ull    /* u64 [8][4096] */
#define CPACK_OFF 42729472ull
#define CCNT_OFF  42991616ull    /* u32 counter (+pad) */
#define CIDX_OFF  42995712ull    /* u32 [CAND_CAP] */
#define CT_OFF    45755712ull    /* u64 [CAND_CAP] */
#define WS_NEEDED 51380224ull    /* layout ends 51,275,712 */

#define CAND_CAP 690000u
#define CMARGIN 2.40f

// lam2 = log2(e) * 10 * (t01*2^-15 + t23*2^-29)  (log2-domain logits)
#define C1L (3.0517578125e-04 * 1.4426950408889634)
#define C2L (1.862645149230957e-08 * 1.4426950408889634)
#define LOG2_02 (-2.3219280948873623)   /* log2(0.2) */

#define CROW(r, kgv) (((r)&3) + 8*((r)>>2) + 4*(kgv))

__device__ __forceinline__ uint32 fkey(float f) {
    uint32 u = __float_as_uint(f);
    return (u & 0x80000000u) ? ~u : (u | 0x80000000u);
}
__device__ __forceinline__ float keyf(uint32 k) {
    uint32 u = (k & 0x80000000u) ? (k ^ 0x80000000u) : ~k;
    return __uint_as_float(u);
}
__device__ __forceinline__ i32x16 mfma_i8(i32x4 a, i32x4 b, i32x16 c) {
    return __builtin_amdgcn_mfma_i32_32x32x32_i8(a, b, c, 0, 0, 0);
}
__device__ __forceinline__ void load_lds16(const char* g, char* l) {
    __builtin_amdgcn_global_load_lds((__attribute__((address_space(1))) void*)(g),
                                     (__attribute__((address_space(3))) void*)(l), 16, 0, 0);
}
__device__ __forceinline__ u64 umax64(u64 a, u64 b) { return a > b ? a : b; }

__global__ void fill_sentinel(float* out, int nelem) {
    int i = blockIdx.x * 256 + threadIdx.x;
    if (i < nelem) out[i] = 12345.0f;
}

__global__ void init_packs(u64* __restrict__ rowpack, u64* __restrict__ colpack,
                           uint32* __restrict__ ccount) {
    int idx = blockIdx.x * 256 + threadIdx.x;
    if (idx < BATCH * LDIM) { rowpack[idx] = 0ull; colpack[idx] = 0ull; }
    if (idx == 0) ccount[0] = 0u;
}

// Quantize fp32 -> 4 exact base-128 signed digits of round(x*2^25).
__global__ __launch_bounds__(256) void quant_kernel(const float* __restrict__ f1,
                                                    const float* __restrict__ f2,
                                                    char* __restrict__ dig)
{
    int tid = blockIdx.x * 256 + threadIdx.x;
    int l31 = tid & 31;
    int kg  = (tid >> 5) & 1;
    int kc  = (tid >> 6) & 3;
    int rb  = (tid >> 8) & 1;
    int blk = (tid >> 9) & 63;
    int n   = (tid >> 15) & 7;
    int inp = tid >> 18;
    int row = blk * 64 + rb * 32 + l31;

    const float* src = (inp ? f2 : f1) + ((size_t)(n * LDIM + row)) * CDIM + kc * 32 + kg * 16;
    char* dstc = dig + (inp ? DIG2_OFF : DIG1_OFF)
               + (((size_t)n * 64 + blk) * 4 + kc) * 8192;
    int gpos = rb * 64 + kg * 32 + l31;

    float4 v0 = ((const float4*)src)[0];
    float4 v1 = ((const float4*)src)[1];
    float4 v2 = ((const float4*)src)[2];
    float4 v3 = ((const float4*)src)[3];
    float xs[16] = {v0.x,v0.y,v0.z,v0.w, v1.x,v1.y,v1.z,v1.w,
                    v2.x,v2.y,v2.z,v2.w, v3.x,v3.y,v3.z,v3.w};
    uint32 wds[4][4] = {{0,0,0,0},{0,0,0,0},{0,0,0,0},{0,0,0,0}};
#pragma unroll
    for (int e = 0; e < 16; e++) {
        int q = __float2int_rn(xs[e] * 33554432.0f);
        int d0 = (q + (1 << 20)) >> 21; q -= d0 << 21;
        int d1 = (q + (1 << 13)) >> 14; q -= d1 << 14;
        int d2 = (q + (1 << 6)) >> 7;   q -= d2 << 7;
        int sh = (e & 3) * 8;
        wds[0][e >> 2] |= (uint32)(d0 & 255) << sh;
        wds[1][e >> 2] |= (uint32)(d1 & 255) << sh;
        wds[2][e >> 2] |= (uint32)(d2 & 255) << sh;
        wds[3][e >> 2] |= (uint32)(q  & 255) << sh;
    }
#pragma unroll
    for (int p = 0; p < 4; p++) {
        *(int4*)(dstc + (size_t)(p * 128 + gpos) * 16) =
            make_int4(wds[p][0], wds[p][1], wds[p][2], wds[p][3]);
    }
}

// FUSED single GEMM pass, 16 waves (1024 thr): each wave owns a 32x32 output
// with all 4 digit banks (acc = 64 regs -> 16 waves/CU resident, 2x latency
// hiding vs the 512-thr/64x32 variant). Stats + candidate emission unchanged.
__global__ __launch_bounds__(1024, 4) void gemm_fused(
    const char* __restrict__ dig,
    float* __restrict__ rpf, float* __restrict__ cpf,
    uint32* __restrict__ ccount, uint32* __restrict__ cidx, u64* __restrict__ ct)
{
    __shared__ __align__(16) char smp[84096];
    // stage: 2 bufs x 32KB @0..65536
    // epilogue reuse: trf f32[128][129] @0 (66048), rstat f2[8][128] @66560,
    // cpart f2[8][128] @74752, rowMaxF[128] @82944, colMaxF[128] @83456,
    // waveTot u32[17] @83968

    int wg = blockIdx.x;
    int swz = (wg & 7) * 1024 + (wg >> 3);    // one batch per XCD
    int n  = swz >> 10;
    int tM = (swz >> 5) & 31;
    int tN = swz & 31;

    const int t = threadIdx.x;
    const int lane = t & 63, w = t >> 6;      // w: 0..15
    const int wr = w >> 2, wc = w & 3;        // 4x4 wave grid of 32x32 tiles
    const int l31 = lane & 31, kg = lane >> 5;

    const i32x16 zero16 = {0,0,0,0,0,0,0,0,0,0,0,0,0,0,0,0};
    i32x16 acc[4];
#pragma unroll
    for (int k = 0; k < 4; k++) acc[k] = zero16;

    auto stage_step = [&](int kc, int buf) {
#pragma unroll
        for (int q = 0; q < 2; q++) {
            int g = t + q * 1024;             // 0..2047 granules of 16B
            int i = g >> 9;                   // 0..3: A0,A1,B0,B1
            int within = g & 511;
            int blk = (i < 2) ? (tM * 2 + i) : (tN * 2 + (i - 2));
            const char* src = dig + ((i < 2) ? DIG1_OFF : DIG2_OFF)
                            + (((size_t)n * 64 + blk) * 4 + kc) * 8192 + within * 16;
            load_lds16(src, smp + buf * 32768 + i * 8192 + within * 16);
        }
    };

    stage_step(0, 0);
    for (int kc = 0; kc < 4; kc++) {
        int buf = kc & 1;
        __syncthreads();
        if (kc < 3) stage_step(kc + 1, buf ^ 1);
        const char* Ab = smp + buf * 32768 + (wr >> 1) * 8192 + (wr & 1) * 1024;
        const char* Bb = smp + buf * 32768 + 16384 + (wc >> 1) * 8192 + (wc & 1) * 1024;
        i32x4 aF[4], bF[4];
#pragma unroll
        for (int p = 0; p < 4; p++) {
            aF[p] = *(const i32x4*)(Ab + p * 2048 + lane * 16);
            bF[p] = *(const i32x4*)(Bb + p * 2048 + lane * 16);
        }
        acc[0] = mfma_i8(aF[0], bF[0], acc[0]);   // T0
        acc[1] = mfma_i8(aF[0], bF[1], acc[1]);   // T1
        acc[1] = mfma_i8(aF[1], bF[0], acc[1]);
        acc[2] = mfma_i8(aF[0], bF[2], acc[2]);   // T2
        acc[2] = mfma_i8(aF[1], bF[1], acc[2]);
        acc[2] = mfma_i8(aF[2], bF[0], acc[2]);
        acc[3] = mfma_i8(aF[0], bF[3], acc[3]);   // T3
        acc[3] = mfma_i8(aF[1], bF[2], acc[3]);
        acc[3] = mfma_i8(aF[2], bF[1], acc[3]);
        acc[3] = mfma_i8(aF[3], bF[0], acc[3]);
    }

    const int col = wc * 32 + l31;

    // exact integer pairs (kept live for emission) + fp32 logits for stats
    int t01v[16], t23v[16];
    float lamf[16];
    const float c1f = (float)C1L, c2f = (float)C2L;
#pragma unroll
    for (int r = 0; r < 16; r++) {
        t01v[r] = acc[0][r] * 128 + acc[1][r];
        t23v[r] = acc[2][r] * 128 + acc[3][r];
        lamf[r] = fmaf((float)t23v[r], c2f, (float)t01v[r] * c1f);
    }

    float* trf = (float*)smp;                       // [128][129]
    float2* rstat = (float2*)(smp + 66560);         // [8][128]
    float2* cpart = (float2*)(smp + 74752);         // [8][128]
    float* rowMaxF = (float*)(smp + 82944);         // [128]
    float* colMaxF = (float*)(smp + 83456);         // [128]
    uint32* waveTot = (uint32*)(smp + 83968);       // [17]

    __syncthreads();   // all frag reads done; stage region reusable

    // ---- phase A: transpose write + col partials ----
#pragma unroll
    for (int r = 0; r < 16; r++) {
        int row = wr * 32 + CROW(r, kg);
        trf[row * 129 + col] = lamf[r];
    }
    {
        float cm = lamf[0];
#pragma unroll
        for (int r = 1; r < 16; r++) cm = fmaxf(cm, lamf[r]);
        float cs = 0.f;
#pragma unroll
        for (int r = 0; r < 16; r++) cs += exp2f(lamf[r] - cm);
        cpart[(wr * 2 + kg) * 128 + col] = make_float2(cm, cs);
    }
    __syncthreads();

    // ---- phase B: per-segment row stats (transpose read), 8 segs x 16 ----
    {
        int row = t & 127, seg = t >> 7;
        const float* rp = trf + row * 129 + seg * 16;
        float v[16];
#pragma unroll
        for (int j = 0; j < 16; j++) v[j] = rp[j];
        float rm = v[0];
#pragma unroll
        for (int j = 1; j < 16; j++) rm = fmaxf(rm, v[j]);
        float rs = 0.f;
#pragma unroll
        for (int j = 0; j < 16; j++) rs += exp2f(v[j] - rm);
        rstat[seg * 128 + row] = make_float2(rm, rs);
    }
    __syncthreads();

    // ---- phase B2: merges (8 contribs) + maxima publish + partial stores ----
    if (t < 128) {
        float2 p0 = rstat[t];
        float M = p0.x;
#pragma unroll
        for (int i = 1; i < 8; i++) M = fmaxf(M, rstat[i * 128 + t].x);
        float S = 0.f;
#pragma unroll
        for (int i = 0; i < 8; i++) {
            float2 p = rstat[i * 128 + t];
            S += p.y * exp2f(p.x - M);
        }
        rowMaxF[t] = M;
        rpf[((size_t)n * LDIM + tM * 128 + t) * 32 + tN] = M + log2f(S);
    } else if (t < 256) {
        int c0 = t - 128;
        float2 p0 = cpart[c0];
        float M = p0.x;
#pragma unroll
        for (int i = 1; i < 8; i++) M = fmaxf(M, cpart[i * 128 + c0].x);
        float S = 0.f;
#pragma unroll
        for (int i = 0; i < 8; i++) {
            float2 p = cpart[i * 128 + c0];
            S += p.y * exp2f(p.x - M);
        }
        colMaxF[c0] = M;
        cpf[((size_t)n * LDIM + tN * 128 + c0) * 32 + tM] = M + log2f(S);
    }
    __syncthreads();   // maxima ready

    // ---- phase C: candidate scan, ONE evaluation -> bitmask ----
    uint32 mask = 0;
    {
        const float cthr = colMaxF[col] - CMARGIN;
#pragma unroll
        for (int r = 0; r < 16; r++) {
            int row = wr * 32 + CROW(r, kg);
            if (lamf[r] >= rowMaxF[row] - CMARGIN && lamf[r] >= cthr)
                mask |= 1u << r;
        }
    }
    uint32 cnt = (uint32)__popc(mask);
    uint32 x = cnt;
#pragma unroll
    for (int d = 1; d < 64; d <<= 1) {
        uint32 y = __shfl_up(x, d);
        if (lane >= d) x += y;
    }
    if (lane == 63) waveTot[w] = x;
    __syncthreads();
    if (t == 0) {
        uint32 s = 0;
#pragma unroll
        for (int i = 0; i < 16; i++) { uint32 v = waveTot[i]; waveTot[i] = s; s += v; }
        waveTot[16] = s ? atomicAdd(ccount, s) : 0u;
    }
    __syncthreads();

    // ---- phase E: emission (static-indexed, mask-gated) ----
    if (mask) {
        uint32 p = waveTot[16] + waveTot[w] + (x - cnt);
        const uint32 colG = (uint32)(tN * 128 + col);
#pragma unroll
        for (int r = 0; r < 16; r++) {
            if (mask & (1u << r)) {
                int row = wr * 32 + CROW(r, kg);
                if (p < CAND_CAP) {
                    cidx[p] = ((uint32)n << 24) | ((uint32)(tM * 128 + row) << 12) | colG;
                    ct[p] = ((u64)(uint32)t01v[r] << 32) | (u64)(uint32)t23v[r];
                }
                p++;
            }
        }
    }
}

__global__ __launch_bounds__(256) void merge_kernel(
    const float* __restrict__ rpf, const float* __restrict__ cpf,
    double* __restrict__ lse_row, double* __restrict__ lse_col)
{
    int idx = blockIdx.x * 256 + threadIdx.x;
    const float* src = (idx < BATCH * LDIM) ? rpf : cpf;
    double* dst = (idx < BATCH * LDIM) ? lse_row : lse_col;
    int i = idx & (BATCH * LDIM - 1);
    float M = -3.4e38f;
#pragma unroll
    for (int j = 0; j < 32; j++) M = fmaxf(M, src[(size_t)i * 32 + j]);
    double S = 0.0;
#pragma unroll
    for (int j = 0; j < 32; j++)
        S += exp2((double)src[(size_t)i * 32 + j] - (double)M);
    dst[i] = (double)M + log2(S);
}

// Exact keys for candidates only; identical gf arithmetic to the fallback.
__global__ __launch_bounds__(256) void finalize_kernel(
    const uint32* __restrict__ cidx, const u64* __restrict__ ct,
    const uint32* __restrict__ ccount,
    const double* __restrict__ lse_row, const double* __restrict__ lse_col,
    u64* __restrict__ rowpack, u64* __restrict__ colpack)
{
    uint32 cnt = ccount[0];
    if (cnt > CAND_CAP) cnt = CAND_CAP;
    uint32 i = blockIdx.x * 256 + threadIdx.x;
    if (i >= cnt) return;
    uint32 id = cidx[i];
    int n = id >> 24, rowG = (id >> 12) & 4095, colG = id & 4095;
    u64 tt = ct[i];
    int t01 = (int)(uint32)(tt >> 32), t23 = (int)(uint32)tt;
    double l2 = (double)t01 * C1L + (double)t23 * C2L;
    float gf = (float)(2.0 * l2 - lse_row[(size_t)n * LDIM + rowG]
                                - lse_col[(size_t)n * LDIM + colG]);
    u64 key = ((u64)fkey(gf)) << 32;
    atomicMax(&rowpack[(size_t)n * LDIM + rowG], key | (uint32)(~(uint32)colG));
    atomicMax(&colpack[(size_t)n * LDIM + colG], key | (uint32)(~(uint32)rowG));
}

// Overflow fallback (round-7 PASS2): full recompute with t01 filter.
// Early-exits unless the candidate buffer overflowed.
__global__ __launch_bounds__(512, 2) void gemm_fallback(
    const char* __restrict__ dig, const uint32* __restrict__ ccount,
    const double* __restrict__ lse_row, const double* __restrict__ lse_col,
    u64* __restrict__ rowpack, u64* __restrict__ colpack)
{
    if (ccount[0] <= CAND_CAP) return;

    __shared__ __align__(16) char smp[68608];
    int wg = blockIdx.x;
    int swz = (wg & 7) * 1024 + (wg >> 3);
    int n  = swz >> 10;
    int tM = (swz >> 5) & 31;
    int tN = swz & 31;

    const int t = threadIdx.x;
    const int lane = t & 63, w = t >> 6;
    const int wr = w >> 2, wc = w & 3;
    const int l31 = lane & 31, kg = lane >> 5;

    double* lserd = (double*)(smp + 65536);
    double* lsecd = (double*)(smp + 66560);
    float*  lserf = (float*)(smp + 67584);
    float*  lsecf = (float*)(smp + 68096);
    if (t < 128) {
        double d = lse_row[(size_t)n * LDIM + tM * 128 + t];
        lserd[t] = d; lserf[t] = (float)d;
    } else if (t < 256) {
        int c = t - 128;
        double d = lse_col[(size_t)n * LDIM + tN * 128 + c];
        lsecd[c] = d; lsecf[c] = (float)d;
    }

    const i32x16 zero16 = {0,0,0,0,0,0,0,0,0,0,0,0,0,0,0,0};
    i32x16 acc[2][4];
#pragma unroll
    for (int sm = 0; sm < 2; sm++)
#pragma unroll
        for (int k = 0; k < 4; k++) acc[sm][k] = zero16;

    auto stage_step = [&](int kc, int buf) {
#pragma unroll
        for (int i = 0; i < 4; i++) {
            int blk = (i < 2) ? (tM * 2 + i) : (tN * 2 + (i - 2));
            const char* src = dig + ((i < 2) ? DIG1_OFF : DIG2_OFF)
                            + (((size_t)n * 64 + blk) * 4 + kc) * 8192 + t * 16;
            load_lds16(src, smp + buf * 32768 + i * 8192 + t * 16);
        }
    };

    stage_step(0, 0);
    for (int kc = 0; kc < 4; kc++) {
        int buf = kc & 1;
        __syncthreads();
        if (kc < 3) stage_step(kc + 1, buf ^ 1);
        const char* Ab = smp + buf * 32768 + wr * 8192;
        const char* Bb = smp + buf * 32768 + 16384 + (wc >> 1) * 8192 + (wc & 1) * 1024;
        i32x4 aF[2][4], bF[4];
#pragma unroll
        for (int p = 0; p < 4; p++)
            bF[p] = *(const i32x4*)(Bb + p * 2048 + lane * 16);
#pragma unroll
        for (int sm = 0; sm < 2; sm++)
#pragma unroll
            for (int p = 0; p < 4; p++)
                aF[sm][p] = *(const i32x4*)(Ab + p * 2048 + sm * 1024 + lane * 16);
#pragma unroll
        for (int sm = 0; sm < 2; sm++) {
            acc[sm][0] = mfma_i8(aF[sm][0], bF[0], acc[sm][0]);
            acc[sm][1] = mfma_i8(aF[sm][0], bF[1], acc[sm][1]);
            acc[sm][1] = mfma_i8(aF[sm][1], bF[0], acc[sm][1]);
            acc[sm][2] = mfma_i8(aF[sm][0], bF[2], acc[sm][2]);
            acc[sm][2] = mfma_i8(aF[sm][1], bF[1], acc[sm][2]);
            acc[sm][2] = mfma_i8(aF[sm][2], bF[0], acc[sm][2]);
            acc[sm][3] = mfma_i8(aF[sm][0], bF[3], acc[sm][3]);
            acc[sm][3] = mfma_i8(aF[sm][1], bF[2], acc[sm][3]);
            acc[sm][3] = mfma_i8(aF[sm][2], bF[1], acc[sm][3]);
            acc[sm][3] = mfma_i8(aF[sm][3], bF[0], acc[sm][3]);
        }
    }
    __syncthreads();

    const int col = wc * 32 + l31;
    const float two_c1f = (float)(2.0 * C1L);
    const float scol = lsecf[col] + (float)LOG2_02 - 17.0f;
    const double lcd = lsecd[col];
#pragma unroll
    for (int sm = 0; sm < 2; sm++)
#pragma unroll
        for (int r = 0; r < 16; r++) {
            int row = wr * 64 + sm * 32 + CROW(r, kg);
            int t01 = acc[sm][0][r] * 128 + acc[sm][1][r];
            float lv = (float)t01 * two_c1f;
            if (lv > lserf[row] + scol) {
                int t23 = acc[sm][2][r] * 128 + acc[sm][3][r];
                double l2 = (double)t01 * C1L + (double)t23 * C2L;
                float gf = (float)(2.0 * l2 - lserd[row] - lcd);
                u64 key = ((u64)fkey(gf)) << 32;
                atomicMax(&rowpack[(size_t)n * LDIM + tM * 128 + row],
                          key | (uint32)(~(uint32)(tN * 128 + col)));
                atomicMax(&colpack[(size_t)n * LDIM + tN * 128 + col],
                          key | (uint32)(~(uint32)(tM * 128 + row)));
            }
        }
}

__global__ __launch_bounds__(256) void out_kernel(
    const float* __restrict__ f1, const float* __restrict__ f2,
    const u64* __restrict__ rowpack, const u64* __restrict__ colpack,
    float* __restrict__ out)
{
    int n = blockIdx.y;
    int l0 = blockIdx.x * 64;
    int t = threadIdx.x;
    __shared__ int s_sh[64];
    __shared__ int m_sh[64];
    __shared__ float tile[64][129];
    if (t < 64) {
        u64 rp = rowpack[(size_t)n * LDIM + l0 + t];
        uint32 skey = (uint32)(rp >> 32);
        uint32 s = (~(uint32)rp) & 4095u;
        u64 cp = colpack[(size_t)n * LDIM + s];
        double g2 = (double)keyf(skey);
        int match = (((uint32)(cp >> 32)) == skey) && (g2 > LOG2_02);
        s_sh[t] = (int)s;
        m_sh[t] = match;
    }
    __syncthreads();
#pragma unroll
    for (int i = 0; i < 32; i++) {
        int idx = i * 256 + t;
        int lloc = idx >> 7, ch = idx & 127;
        float v = f1[((size_t)n * LDIM + l0 + lloc) * CDIM + ch];
        if (m_sh[lloc]) v -= f2[((size_t)n * LDIM + s_sh[lloc]) * CDIM + ch];
        tile[lloc][ch] = v;
    }
    __syncthreads();
#pragma unroll
    for (int i = 0; i < 32; i++) {
        int ch = i * 4 + (t >> 6), lw = t & 63;
        out[((size_t)n * CDIM + ch) * LDIM + l0 + lw] = tile[lw][ch];
    }
}

extern "C" void kernel_launch(void* const* d_in, const int* in_sizes, int n_in,
                              void* d_out, int out_size, void* d_ws, size_t ws_size,
                              hipStream_t stream)
{
    const float* f1 = (const float*)d_in[0];
    const float* f2 = (const float*)d_in[1];
    float* out = (float*)d_out;
    char* ws = (char*)d_ws;
    char* dig = ws;

    if (ws_size < WS_NEEDED) {
        fill_sentinel<<<(out_size + 255) / 256, 256, 0, stream>>>(out, out_size);
        return;
    }

    float* rpf      = (float*)(ws + RPF_OFF);
    float* cpf      = (float*)(ws + CPF_OFF);
    double* lse_row = (double*)(ws + LSER_OFF);
    double* lse_col = (double*)(ws + LSEC_OFF);
    u64* rowpack    = (u64*)(ws + RPACK_OFF);
    u64* colpack    = (u64*)(ws + CPACK_OFF);
    uint32* ccount  = (uint32*)(ws + CCNT_OFF);
    uint32* cidx    = (uint32*)(ws + CIDX_OFF);
    u64* ct         = (u64*)(ws + CT_OFF);

    quant_kernel<<<dim3(2048), dim3(256), 0, stream>>>(f1, f2, dig);
    init_packs<<<dim3(128), dim3(256), 0, stream>>>(rowpack, colpack, ccount);
    gemm_fused<<<dim3(8192), dim3(1024), 0, stream>>>(dig, rpf, cpf, ccount, cidx, ct);
    merge_kernel<<<dim3(256), dim3(256), 0, stream>>>(rpf, cpf, lse_row, lse_col);
    finalize_kernel<<<dim3((CAND_CAP + 255) / 256), dim3(256), 0, stream>>>(
        cidx, ct, ccount, lse_row, lse_col, rowpack, colpack);
    gemm_fallback<<<dim3(8192), dim3(512), 0, stream>>>(
        dig, ccount, lse_row, lse_col, rowpack, colpack);
    out_kernel<<<dim3(LDIM / 64, BATCH), dim3(256), 0, stream>>>(
        f1, f2, rowpack, colpack, out);
}